// Round 2
// baseline (3620.811 us; speedup 1.0000x reference)
//
#include <hip/hip_runtime.h>
#include <hip/hip_cooperative_groups.h>

namespace cg = cooperative_groups;

// 1D Euler, Roe flux + Harten entropy fix, 32 first-order Euler steps.
// Round 2: single COOPERATIVE kernel. 32 dependent kernel launches (18 us
// each, ~12 us of which was launch/drain overhead) become 32 grid.sync()s.
//  - State as PRIMITIVES (rho,u,p) ping-ponged between d_out (even states)
//    and d_ws (odd states); state_32 lands in d_out, no final copy.
//  - Per-step global dt: each block publishes its partial max of |u|+c for
//    step k+1 during step k's update; after grid.sync every block reduces
//    the 1024 partials redundantly (4 KB, L2-hot). t lives in a register —
//    every block computes the identical dt sequence.
//  - gamma-1 = 0.4f literal (matches float32(1.4-1.0)). Numerics identical
//    to the round-1 passing kernel.

#define NXC   1048576
#define BLK   256
#define TILE  1024
#define NBLK  (NXC / TILE)   // 1024 blocks = 4/CU, co-resident (LDS 24.1 KB)
#define GAM   1.4f
#define GM1   0.4f
#define CFLC  0.5f
#define DXC   1e-3f
#define EFIX  0.1f
#define NSTEPS 32

__device__ __forceinline__ void roe_flux(float rL, float uL, float pL,
                                         float rR, float uR, float pR,
                                         float& Fr, float& Fm, float& Fe) {
    float EL = pL / GM1 + 0.5f * rL * uL * uL;
    float ER = pR / GM1 + 0.5f * rR * uR * uR;
    float HL = (EL + pL) / rL;
    float HR = (ER + pR) / rR;
    float sL = sqrtf(rL);
    float sR = sqrtf(rR);
    float den = sL + sR;
    float ur = (sL * uL + sR * uR) / den;
    float Hr = (sL * HL + sR * HR) / den;
    float c  = sqrtf(fmaxf(GM1 * (Hr - 0.5f * ur * ur), 1e-10f));
    float eps = EFIX * c;
    float l1 = ur - c;
    float l3 = ur + c;
    float a1 = sqrtf(l1 * l1 + eps * eps);
    float a2 = sqrtf(ur * ur + eps * eps);
    float a3 = sqrtf(l3 * l3 + eps * eps);
    float drho = rR - rL;
    float du   = uR - uL;
    float dp   = pR - pL;
    float c2 = c * c;
    float al2 = drho - dp / c2;
    float al1 = (dp - c * rR * du) / (2.f * c2);
    float al3 = (dp + c * rR * du) / (2.f * c2);
    float FrL = rL * uL, FmL = rL * uL * uL + pL, FeL = uL * (EL + pL);
    float FrR = rR * uR, FmR = rR * uR * uR + pR, FeR = uR * (ER + pR);
    float dr = a1 * al1 + a2 * al2 + a3 * al3;
    float dm = a1 * al1 * l1 + a2 * al2 * ur + a3 * al3 * l3;
    float de = a1 * al1 * (Hr - ur * c) + a2 * al2 * 0.5f * ur * ur
             + a3 * al3 * (Hr + ur * c);
    Fr = 0.5f * (FrL + FrR - dr);
    Fm = 0.5f * (FmL + FmR - dm);
    Fe = 0.5f * (FeL + FeR - de);
}

__device__ __forceinline__ float wave_max(float v) {
    #pragma unroll
    for (int k = 32; k >= 1; k >>= 1)
        v = fmaxf(v, __shfl_xor(v, k));
    return v;
}

__global__ __launch_bounds__(BLK) void euler_coop(
        const float* __restrict__ rho0, const float* __restrict__ u0,
        const float* __restrict__ p0, const float* __restrict__ tf,
        float* __restrict__ A,   // even states (= d_out)
        float* __restrict__ B,   // odd states (in d_ws)
        float* __restrict__ part) {
    cg::grid_group grid = cg::this_grid();
    __shared__ float r[TILE + 2], uu[TILE + 2], pp[TILE + 2];
    __shared__ float Fr[TILE + 1], Fm[TILE + 1], Fe[TILE + 1];
    __shared__ float red[BLK / 64];
    const int tid  = threadIdx.x;
    const int bid  = blockIdx.x;
    const int base = bid * TILE;

    // ---- init: inputs -> state_0 (primitives, in A); partial max |u|+c ----
    float lm = 0.f;
    for (int j = tid; j < TILE; j += BLK) {
        int g = base + j;
        float r_ = rho0[g], u_ = u0[g], p_ = p0[g];
        A[g] = r_;
        A[NXC + g] = u_;
        A[2 * NXC + g] = p_;
        lm = fmaxf(lm, fabsf(u_) + sqrtf(GAM * p_ / r_));
    }
    lm = wave_max(lm);
    if ((tid & 63) == 0) red[tid >> 6] = lm;
    __syncthreads();
    if (tid == 0)
        part[bid] = fmaxf(fmaxf(red[0], red[1]), fmaxf(red[2], red[3]));
    float t = 0.f;
    const float tfin = *tf;
    grid.sync();

    for (int k = 0; k < NSTEPS; ++k) {
        const float* src  = (k & 1) ? B : A;
        float*       dst  = (k & 1) ? A : B;
        const float* pin  = part + (size_t)(k & 1) * NBLK;
        float*       pout = part + (size_t)((k + 1) & 1) * NBLK;

        // partial-max reduction for dt (redundant per block; 4 KB, L2-hot)
        float m = 0.f;
        #pragma unroll
        for (int i = tid; i < NBLK; i += BLK) m = fmaxf(m, pin[i]);

        // stage tile + halo primitives into LDS (replicated edge ghosts)
        for (int i = tid; i < TILE + 2; i += BLK) {
            int g = base - 1 + i;
            g = max(0, min(NXC - 1, g));
            r[i]  = src[g];
            uu[i] = src[NXC + g];
            pp[i] = src[2 * NXC + g];
        }

        m = wave_max(m);
        if ((tid & 63) == 0) red[tid >> 6] = m;
        __syncthreads();   // covers red[] and the LDS state stage

        float amax = fmaxf(fmaxf(red[0], red[1]), fmaxf(red[2], red[3]));
        float dt = fminf((CFLC * DXC) / amax, fmaxf(tfin - t, 0.f));
        t += dt;
        float dtdx = dt / DXC;

        // one flux per interface
        for (int i = tid; i < TILE + 1; i += BLK)
            roe_flux(r[i], uu[i], pp[i], r[i + 1], uu[i + 1], pp[i + 1],
                     Fr[i], Fm[i], Fe[i]);
        __syncthreads();

        // conservative update, back to primitives, next-step partial max
        float nm = 0.f;
        for (int j = tid; j < TILE; j += BLK) {
            float rho = r[j + 1], u = uu[j + 1], p = pp[j + 1];
            float E    = p / GM1 + 0.5f * rho * u * u;
            float rho2  = rho     - dtdx * (Fr[j + 1] - Fr[j]);
            float rhou2 = rho * u - dtdx * (Fm[j + 1] - Fm[j]);
            float E2    = E       - dtdx * (Fe[j + 1] - Fe[j]);
            float u2 = rhou2 / rho2;
            float p2 = GM1 * (E2 - 0.5f * rho2 * u2 * u2);
            int g = base + j;
            dst[g] = rho2;
            dst[NXC + g] = u2;
            dst[2 * NXC + g] = p2;
            nm = fmaxf(nm, fabsf(u2) + sqrtf(GAM * p2 / rho2));
        }
        nm = wave_max(nm);
        __syncthreads();              // red[] reads (amax) all done pre-flux
        if ((tid & 63) == 0) red[tid >> 6] = nm;
        __syncthreads();
        if (tid == 0)
            pout[bid] = fmaxf(fmaxf(red[0], red[1]), fmaxf(red[2], red[3]));
        grid.sync();                  // state_{k+1} + partials visible
    }
    // NSTEPS even -> state_32 is in A = d_out as [rho | u | p]. Done.
}

extern "C" void kernel_launch(void* const* d_in, const int* in_sizes, int n_in,
                              void* d_out, int out_size, void* d_ws, size_t ws_size,
                              hipStream_t stream) {
    const float* rho0 = (const float*)d_in[0];
    const float* u0   = (const float*)d_in[1];
    const float* p0   = (const float*)d_in[2];
    const float* tf   = (const float*)d_in[3];
    // d_in[4] = n_steps (fixed at 32 for this problem)

    float* A    = (float*)d_out;               // even states
    float* B    = (float*)d_ws;                // odd states (3*NX floats)
    float* part = B + (size_t)3 * NXC;         // 2 * NBLK partial maxima

    void* args[] = {(void*)&rho0, (void*)&u0, (void*)&p0, (void*)&tf,
                    (void*)&A, (void*)&B, (void*)&part};
    hipLaunchCooperativeKernel((void*)euler_coop, dim3(NBLK), dim3(BLK),
                               args, 0, stream);
}

// Round 3
// 2706.041 us; speedup vs baseline: 1.3380x; 1.3380x over previous
//
#include <hip/hip_runtime.h>

// 1D Euler, Roe flux + Harten entropy fix, 32 steps. Round 3:
// persistent cooperative kernel with a HAND-ROLLED two-level global barrier
// (cg::grid.sync measured ~100 us/step in round 2 -- pure protocol cost:
// VALUBusy 10%, HBM 1.5%). Plus per-cell precompute (sqrt/div work was done
// twice per cell as L/R of adjacent interfaces) and init folded into step 0.
//  - States as primitives; even states in d_out (A), odd in d_ws (B);
//    step k reads state_k (k=0: raw inputs), writes state_{k+1};
//    state_32 lands in d_out. 
//  - Barrier: monotonic counters (no reset races): 64 padded L1 counters
//    (16 blocks each) -> 1 L2 counter -> generation flag. Thread-0 only,
//    agent-scope acq/rel atomics, s_sleep backoff, __syncthreads broadcast.
//    Counters zeroed by a 1-block kernel node before the cooperative node
//    (d_ws is re-poisoned 0xAA before every timed call).
//  - gamma-1 = 0.4f (best f32 of 0.4; matched np ref at absmax 0.0078).

#define NXC   1048576
#define BLK   256
#define TILE  1024
#define NBLK  (NXC / TILE)   // 1024 blocks = 4/CU (LDS 36.9 KB -> 4/CU cap)
#define GAM   1.4f
#define GM1   0.4f
#define CFLC  0.5f
#define DXC   1e-3f
#define EFIX  0.1f
#define NSTEPS 32

#define BAR1_N     64        // level-1 counters (16 blocks each)
#define BAR_STRIDE 32        // 128 B padding between counters

__device__ __forceinline__ float wave_max(float v) {
    #pragma unroll
    for (int k = 32; k >= 1; k >>= 1)
        v = fmaxf(v, __shfl_xor(v, k));
    return v;
}

// Two-level grid barrier. Every block calls with the same, strictly
// increasing gen (1,2,3,...). Counters are monotonic: per gen each L1
// counter advances by 16, L2 by 64; leaders fire on (old mod N)==N-1.
__device__ __forceinline__ void gbar(unsigned* bar1, unsigned* bar2,
                                     unsigned* flag, int bid, unsigned gen) {
    __syncthreads();   // block's stores issued (s_barrier drains vmcnt)
    if (threadIdx.x == 0) {
        unsigned o = __hip_atomic_fetch_add(&bar1[(bid & (BAR1_N - 1)) * BAR_STRIDE],
                                            1u, __ATOMIC_ACQ_REL,
                                            __HIP_MEMORY_SCOPE_AGENT);
        if ((o & 15u) == 15u) {
            unsigned o2 = __hip_atomic_fetch_add(bar2, 1u, __ATOMIC_ACQ_REL,
                                                 __HIP_MEMORY_SCOPE_AGENT);
            if ((o2 & 63u) == 63u)
                __hip_atomic_store(flag, gen, __ATOMIC_RELEASE,
                                   __HIP_MEMORY_SCOPE_AGENT);
        }
        while (__hip_atomic_load(flag, __ATOMIC_ACQUIRE,
                                 __HIP_MEMORY_SCOPE_AGENT) < gen)
            __builtin_amdgcn_s_sleep(1);
    }
    __syncthreads();   // broadcast: teammates ordered after thread-0 acquire
}

__global__ void bar_zero(unsigned* bar) {
    for (int i = threadIdx.x; i < BAR1_N * BAR_STRIDE + 2 * BAR_STRIDE; i += BLK)
        bar[i] = 0u;
}

__global__ __launch_bounds__(BLK, 4) void euler_coop(
        const float* __restrict__ rho0, const float* __restrict__ u0,
        const float* __restrict__ p0, const float* __restrict__ tf,
        float* __restrict__ A,      // even states (= d_out)
        float* __restrict__ B,      // odd states (in d_ws)
        float* __restrict__ part,   // 2 * NBLK partial maxima
        unsigned* __restrict__ bar) {
    __shared__ float sr[TILE + 2], su[TILE + 2], sp[TILE + 2];
    __shared__ float ss[TILE + 2], sg[TILE + 2], sfr[TILE + 2];
    __shared__ float fFr[TILE + 1], fFm[TILE + 1], fFe[TILE + 1];
    __shared__ float red[BLK / 64];
    unsigned* bar1 = bar;
    unsigned* bar2 = bar + BAR1_N * BAR_STRIDE;
    unsigned* flag = bar + (BAR1_N + 1) * BAR_STRIDE;

    const int tid  = threadIdx.x;
    const int bid  = blockIdx.x;
    const int base = bid * TILE;
    unsigned gen = 0;

    // ---- pre-pass: partial max of |u0|+c0 (no state copy) ----
    float lm = 0.f;
    for (int j = tid; j < TILE; j += BLK) {
        int g = base + j;
        lm = fmaxf(lm, fabsf(u0[g]) + sqrtf(GAM * p0[g] / rho0[g]));
    }
    lm = wave_max(lm);
    if ((tid & 63) == 0) red[tid >> 6] = lm;
    __syncthreads();
    if (tid == 0)
        part[bid] = fmaxf(fmaxf(red[0], red[1]), fmaxf(red[2], red[3]));
    float t = 0.f;
    const float tfin = *tf;
    gbar(bar1, bar2, flag, bid, ++gen);

    for (int k = 0; k < NSTEPS; ++k) {
        // state_k source pointers (k=0: raw inputs; else ping-pong buffer)
        const float *rs, *us, *ps;
        if (k == 0) { rs = rho0; us = u0; ps = p0; }
        else {
            const float* s_ = (k & 1) ? B : A;
            rs = s_; us = s_ + NXC; ps = s_ + 2 * NXC;
        }
        float*       dst  = (k & 1) ? A : B;
        const float* pin  = part + (size_t)(k & 1) * NBLK;
        float*       pout = part + (size_t)((k + 1) & 1) * NBLK;

        // dt partial-max loads (issue early, redundant per block, L2-hot)
        float m = 0.f;
        #pragma unroll
        for (int i = tid; i < NBLK; i += BLK) m = fmaxf(m, pin[i]);

        // per-CELL precompute into LDS (tile + replicated-edge halo):
        //   sr,su,sp = rho,u,p ; ss = sqrt(rho) ; sg = (E+p)/sqrt(rho)
        //   sfr = rho*u          [each cell's sqrt/div work done ONCE]
        for (int i = tid; i < TILE + 2; i += BLK) {
            int g = base - 1 + i;
            g = max(0, min(NXC - 1, g));
            float r_ = rs[g], u_ = us[g], p_ = ps[g];
            float E  = p_ / GM1 + 0.5f * r_ * u_ * u_;
            float s_ = sqrtf(r_);
            sr[i] = r_; su[i] = u_; sp[i] = p_;
            ss[i] = s_;
            sg[i] = (E + p_) / s_;      // = sqrt(r)*H
            sfr[i] = r_ * u_;
        }

        m = wave_max(m);
        if ((tid & 63) == 0) red[tid >> 6] = m;
        __syncthreads();    // covers red[] and LDS precompute

        float amax = fmaxf(fmaxf(red[0], red[1]), fmaxf(red[2], red[3]));
        float dt = fminf((CFLC * DXC) / amax, fmaxf(tfin - t, 0.f));
        t += dt;
        float dtdx = dt / DXC;

        // one Roe flux per interface
        for (int i = tid; i < TILE + 1; i += BLK) {
            float sL = ss[i], sR = ss[i + 1];
            float uL = su[i], uR = su[i + 1];
            float invden = 1.f / (sL + sR);
            float ur = (sL * uL + sR * uR) * invden;
            float Hr = (sg[i] + sg[i + 1]) * invden;
            float c  = sqrtf(fmaxf(GM1 * (Hr - 0.5f * ur * ur), 1e-10f));
            float eps = EFIX * c;
            float l1 = ur - c, l3 = ur + c;
            float a1 = sqrtf(l1 * l1 + eps * eps);
            float a2 = sqrtf(ur * ur + eps * eps);
            float a3 = sqrtf(l3 * l3 + eps * eps);
            float drho = sr[i + 1] - sr[i];
            float du   = uR - uL;
            float dp   = sp[i + 1] - sp[i];
            float c2 = c * c;
            float inv2c2 = 1.f / (c2 + c2);
            float al2 = drho - (dp + dp) * inv2c2;
            float tcd = c * sr[i + 1] * du;
            float al1 = (dp - tcd) * inv2c2;
            float al3 = (dp + tcd) * inv2c2;
            float FrL = sfr[i], FrR = sfr[i + 1];
            float FmL = FrL * uL + sp[i], FmR = FrR * uR + sp[i + 1];
            float FeL = uL * (sg[i] * sL), FeR = uR * (sg[i + 1] * sR);
            float w1 = a1 * al1, w2 = a2 * al2, w3 = a3 * al3;
            float dr = w1 + w2 + w3;
            float dm = w1 * l1 + w2 * ur + w3 * l3;
            float de = w1 * (Hr - ur * c) + w2 * (0.5f * ur * ur)
                     + w3 * (Hr + ur * c);
            fFr[i] = 0.5f * (FrL + FrR - dr);
            fFm[i] = 0.5f * (FmL + FmR - dm);
            fFe[i] = 0.5f * (FeL + FeR - de);
        }
        __syncthreads();

        // conservative update -> primitives; next-step partial max
        float nm = 0.f;
        for (int j = tid; j < TILE; j += BLK) {
            float rho = sr[j + 1], u = su[j + 1], p = sp[j + 1];
            float E = sg[j + 1] * ss[j + 1] - p;          // (E+p) - p
            float rho2  = rho        - dtdx * (fFr[j + 1] - fFr[j]);
            float rhou2 = sfr[j + 1] - dtdx * (fFm[j + 1] - fFm[j]);
            float E2    = E          - dtdx * (fFe[j + 1] - fFe[j]);
            float u2 = rhou2 / rho2;
            float p2 = GM1 * (E2 - 0.5f * rho2 * u2 * u2);
            int g = base + j;
            dst[g] = rho2;
            dst[NXC + g] = u2;
            dst[2 * NXC + g] = p2;
            nm = fmaxf(nm, fabsf(u2) + sqrtf(GAM * p2 / rho2));
        }
        nm = wave_max(nm);            // red[] last read pre-flux: safe
        if ((tid & 63) == 0) red[tid >> 6] = nm;
        __syncthreads();
        if (tid == 0)
            pout[bid] = fmaxf(fmaxf(red[0], red[1]), fmaxf(red[2], red[3]));

        if (k < NSTEPS - 1) gbar(bar1, bar2, flag, bid, ++gen);
    }
    // state_32 is in A = d_out as [rho | u | p]. Done.
}

extern "C" void kernel_launch(void* const* d_in, const int* in_sizes, int n_in,
                              void* d_out, int out_size, void* d_ws, size_t ws_size,
                              hipStream_t stream) {
    const float* rho0 = (const float*)d_in[0];
    const float* u0   = (const float*)d_in[1];
    const float* p0   = (const float*)d_in[2];
    const float* tf   = (const float*)d_in[3];
    // d_in[4] = n_steps (fixed at 32)

    float* A    = (float*)d_out;
    float* B    = (float*)d_ws;                       // 3*NXC floats
    float* part = B + (size_t)3 * NXC;                // 2*NBLK floats
    unsigned* bar = (unsigned*)(part + 2 * NBLK);     // (64+2)*32 uints

    bar_zero<<<1, BLK, 0, stream>>>(bar);

    void* args[] = {(void*)&rho0, (void*)&u0, (void*)&p0, (void*)&tf,
                    (void*)&A, (void*)&B, (void*)&part, (void*)&bar};
    hipLaunchCooperativeKernel((void*)euler_coop, dim3(NBLK), dim3(BLK),
                               args, 0, stream);
}

// Round 4
// 541.985 us; speedup vs baseline: 6.6807x; 4.9928x over previous
//
#include <hip/hip_runtime.h>

// 1D Euler, Roe flux + Harten entropy fix, 32 steps. Round 4:
// persistent kernel with XCD-LOCAL state + tiny system-scope halo exchange.
//
// Round-3 evidence: agent-scope acq/rel barrier ops trigger buffer_wbl2 /
// buffer_inv (full L2 flush+inv) on gfx950 -> WRITE_SIZE showed the entire
// 12 MB state hitting HBM every step and 84 us/step of serialized cache
// maintenance. Fix:
//  - A block only ever touches ITS OWN tile with plain cached accesses.
//    Persistent blocks never migrate, so own-tile RAW across steps is
//    same-L2 coherent. 24 MB ping-pong = 3 MB/XCD stays L2-resident.
//  - Cross-block data per step is tiny: 2 halo cells/block (24 B), 1024
//    partial maxima (4 KB), barrier words. These use RELAXED SYSTEM-scope
//    atomics (global_* sc0 sc1: bypass L1/L2, served by the coherent
//    memory-side Infinity Cache). Relaxed => compiler emits NO inv/wbl2.
//    Ordering: __syncthreads drains vmcnt per wave before barrier arrival.
//  - Barrier: monotonic two-level counters (64 padded L1 -> 1 L2 -> gen
//    flag), thread-0 only, s_sleep backoff. Zeroed by a pre-node kernel.
//  - gamma-1 = 0.4f literal; flux math identical to the passing round-3.

#define NXC   1048576
#define BLK   256
#define TILE  1024
#define NBLK  (NXC / TILE)   // 1024 blocks = 4/CU co-resident (LDS 37 KB)
#define GAM   1.4f
#define GM1   0.4f
#define CFLC  0.5f
#define DXC   1e-3f
#define EFIX  0.1f
#define NSTEPS 32

#define BAR1_N  64
#define BSTRIDE 32           // 128 B between counters

__device__ __forceinline__ float sysloadf(const float* p) {
    return __hip_atomic_load(p, __ATOMIC_RELAXED, __HIP_MEMORY_SCOPE_SYSTEM);
}
__device__ __forceinline__ void sysstoref(float* p, float v) {
    __hip_atomic_store(p, v, __ATOMIC_RELAXED, __HIP_MEMORY_SCOPE_SYSTEM);
}

__device__ __forceinline__ float wave_max(float v) {
    #pragma unroll
    for (int k = 32; k >= 1; k >>= 1)
        v = fmaxf(v, __shfl_xor(v, k));
    return v;
}

// Relaxed system-scope two-level barrier. gen strictly increasing from 1.
__device__ __forceinline__ void gbar(unsigned* bar1, unsigned* bar2,
                                     unsigned* flag, int bid, unsigned gen) {
    __syncthreads();   // every wave drains vmcnt(0) before arriving
    if (threadIdx.x == 0) {
        unsigned o = __hip_atomic_fetch_add(
            &bar1[(bid & (BAR1_N - 1)) * BSTRIDE], 1u,
            __ATOMIC_RELAXED, __HIP_MEMORY_SCOPE_SYSTEM);
        if ((o & 15u) == 15u) {
            unsigned o2 = __hip_atomic_fetch_add(
                bar2, 1u, __ATOMIC_RELAXED, __HIP_MEMORY_SCOPE_SYSTEM);
            if ((o2 & 63u) == 63u)
                __hip_atomic_store(flag, gen, __ATOMIC_RELAXED,
                                   __HIP_MEMORY_SCOPE_SYSTEM);
        }
        while (__hip_atomic_load(flag, __ATOMIC_RELAXED,
                                 __HIP_MEMORY_SCOPE_SYSTEM) < gen)
            __builtin_amdgcn_s_sleep(2);
    }
    __syncthreads();
}

__global__ void bar_zero(unsigned* bar) {
    for (int i = threadIdx.x; i < (BAR1_N + 2) * BSTRIDE; i += BLK)
        bar[i] = 0u;
}

__global__ __launch_bounds__(BLK, 4) void euler_pers(
        const float* __restrict__ rho0, const float* __restrict__ u0,
        const float* __restrict__ p0, const float* __restrict__ tf,
        float* __restrict__ A,      // even states (= d_out)
        float* __restrict__ B,      // odd states (in d_ws)
        float* __restrict__ part,   // 2 * NBLK partial maxima (IC-resident)
        float* __restrict__ halo,   // 2 * NBLK * 6 halo floats (IC-resident)
        unsigned* __restrict__ bar) {
    __shared__ float sr[TILE + 2], su[TILE + 2], sp[TILE + 2];
    __shared__ float ss[TILE + 2], sg[TILE + 2], sfr[TILE + 2];
    __shared__ float fFr[TILE + 1], fFm[TILE + 1], fFe[TILE + 1];
    __shared__ float red[BLK / 64];
    unsigned* bar1 = bar;
    unsigned* bar2 = bar + BAR1_N * BSTRIDE;
    unsigned* flag = bar + (BAR1_N + 1) * BSTRIDE;

    const int tid  = threadIdx.x;
    const int bid  = blockIdx.x;
    const int base = bid * TILE;
    unsigned gen = 0;

    // ---- prepass: partial max of |u0|+c0 (inputs are read-only: coherent)
    float lm = 0.f;
    for (int j = tid; j < TILE; j += BLK) {
        int g = base + j;
        lm = fmaxf(lm, fabsf(u0[g]) + sqrtf(GAM * p0[g] / rho0[g]));
    }
    lm = wave_max(lm);
    if ((tid & 63) == 0) red[tid >> 6] = lm;
    __syncthreads();
    if (tid == 0)
        sysstoref(&part[bid],
                  fmaxf(fmaxf(red[0], red[1]), fmaxf(red[2], red[3])));
    float t = 0.f;
    const float tfin = *tf;
    gbar(bar1, bar2, flag, bid, ++gen);

    for (int k = 0; k < NSTEPS; ++k) {
        const int pk = k & 1;
        const float* src  = pk ? B : A;     // own tile only (k>=1)
        float*       dst  = pk ? A : B;     // own tile only
        const float* pin  = part + (size_t)pk * NBLK;
        float*       pout = part + (size_t)(1 - pk) * NBLK;
        const float* hin  = halo + (size_t)pk * (NBLK * 6);
        float*       hout = halo + (size_t)(1 - pk) * (NBLK * 6);

        // dt partial-max loads (4 KB from IC, 4 independent loads/thread)
        float m = 0.f;
        #pragma unroll
        for (int i = tid; i < NBLK; i += BLK) m = fmaxf(m, sysloadf(pin + i));

        // stage tile + halo into LDS with per-cell precompute:
        //   ss = sqrt(rho), sg = (E+p)/sqrt(rho) = sqrt(rho)*H, sfr = rho*u
        for (int i = tid; i < TILE + 2; i += BLK) {
            float r_, u_, p_;
            if (k == 0) {                       // step 0: raw inputs
                int g = max(0, min(NXC - 1, base - 1 + i));
                r_ = rho0[g]; u_ = u0[g]; p_ = p0[g];
            } else if (i == 0) {                // left ghost
                if (bid == 0) {
                    r_ = src[base]; u_ = src[NXC + base]; p_ = src[2 * NXC + base];
                } else {
                    const float* h = hin + (size_t)(bid - 1) * 6 + 3;
                    r_ = sysloadf(h); u_ = sysloadf(h + 1); p_ = sysloadf(h + 2);
                }
            } else if (i == TILE + 1) {         // right ghost
                if (bid == NBLK - 1) {
                    int g = base + TILE - 1;
                    r_ = src[g]; u_ = src[NXC + g]; p_ = src[2 * NXC + g];
                } else {
                    const float* h = hin + (size_t)(bid + 1) * 6;
                    r_ = sysloadf(h); u_ = sysloadf(h + 1); p_ = sysloadf(h + 2);
                }
            } else {                            // own tile (local L2)
                int g = base + i - 1;
                r_ = src[g]; u_ = src[NXC + g]; p_ = src[2 * NXC + g];
            }
            float E  = p_ / GM1 + 0.5f * r_ * u_ * u_;
            float s_ = sqrtf(r_);
            sr[i] = r_; su[i] = u_; sp[i] = p_;
            ss[i] = s_; sg[i] = (E + p_) / s_; sfr[i] = r_ * u_;
        }

        m = wave_max(m);
        if ((tid & 63) == 0) red[tid >> 6] = m;
        __syncthreads();    // covers red[] + LDS staging

        float amax = fmaxf(fmaxf(red[0], red[1]), fmaxf(red[2], red[3]));
        float dt = fminf((CFLC * DXC) / amax, fmaxf(tfin - t, 0.f));
        t += dt;
        float dtdx = dt / DXC;

        // one Roe flux per interface
        for (int i = tid; i < TILE + 1; i += BLK) {
            float sL = ss[i], sR = ss[i + 1];
            float uL = su[i], uR = su[i + 1];
            float invden = 1.f / (sL + sR);
            float ur = (sL * uL + sR * uR) * invden;
            float Hr = (sg[i] + sg[i + 1]) * invden;
            float c  = sqrtf(fmaxf(GM1 * (Hr - 0.5f * ur * ur), 1e-10f));
            float eps = EFIX * c;
            float l1 = ur - c, l3 = ur + c;
            float a1 = sqrtf(l1 * l1 + eps * eps);
            float a2 = sqrtf(ur * ur + eps * eps);
            float a3 = sqrtf(l3 * l3 + eps * eps);
            float drho = sr[i + 1] - sr[i];
            float du   = uR - uL;
            float dp   = sp[i + 1] - sp[i];
            float c2 = c * c;
            float inv2c2 = 1.f / (c2 + c2);
            float al2 = drho - (dp + dp) * inv2c2;
            float tcd = c * sr[i + 1] * du;
            float al1 = (dp - tcd) * inv2c2;
            float al3 = (dp + tcd) * inv2c2;
            float FrL = sfr[i], FrR = sfr[i + 1];
            float FmL = FrL * uL + sp[i], FmR = FrR * uR + sp[i + 1];
            float FeL = uL * (sg[i] * sL), FeR = uR * (sg[i + 1] * sR);
            float w1 = a1 * al1, w2 = a2 * al2, w3 = a3 * al3;
            float dr = w1 + w2 + w3;
            float dm = w1 * l1 + w2 * ur + w3 * l3;
            float de = w1 * (Hr - ur * c) + w2 * (0.5f * ur * ur)
                     + w3 * (Hr + ur * c);
            fFr[i] = 0.5f * (FrL + FrR - dr);
            fFm[i] = 0.5f * (FmL + FmR - dm);
            fFe[i] = 0.5f * (FeL + FeR - de);
        }
        __syncthreads();

        // conservative update -> primitives (own tile, cached stores);
        // edge cells also go to the system-scope halo slots.
        float nm = 0.f;
        for (int j = tid; j < TILE; j += BLK) {
            float rho = sr[j + 1], u = su[j + 1], p = sp[j + 1];
            float E = sg[j + 1] * ss[j + 1] - p;          // (E+p) - p
            float rho2  = rho        - dtdx * (fFr[j + 1] - fFr[j]);
            float rhou2 = sfr[j + 1] - dtdx * (fFm[j + 1] - fFm[j]);
            float E2    = E          - dtdx * (fFe[j + 1] - fFe[j]);
            float u2 = rhou2 / rho2;
            float p2 = GM1 * (E2 - 0.5f * rho2 * u2 * u2);
            int g = base + j;
            dst[g] = rho2;
            dst[NXC + g] = u2;
            dst[2 * NXC + g] = p2;
            if (j == 0) {
                float* h = hout + (size_t)bid * 6;
                sysstoref(h, rho2); sysstoref(h + 1, u2); sysstoref(h + 2, p2);
            }
            if (j == TILE - 1) {
                float* h = hout + (size_t)bid * 6 + 3;
                sysstoref(h, rho2); sysstoref(h + 1, u2); sysstoref(h + 2, p2);
            }
            nm = fmaxf(nm, fabsf(u2) + sqrtf(GAM * p2 / rho2));
        }
        nm = wave_max(nm);            // red[] last read before flux loop: safe
        if ((tid & 63) == 0) red[tid >> 6] = nm;
        __syncthreads();
        if (tid == 0)
            sysstoref(&pout[bid],
                      fmaxf(fmaxf(red[0], red[1]), fmaxf(red[2], red[3])));

        if (k < NSTEPS - 1) gbar(bar1, bar2, flag, bid, ++gen);
    }
    // k=31 wrote dst=A=d_out; end-of-kernel flush makes it host-visible.
}

extern "C" void kernel_launch(void* const* d_in, const int* in_sizes, int n_in,
                              void* d_out, int out_size, void* d_ws, size_t ws_size,
                              hipStream_t stream) {
    const float* rho0 = (const float*)d_in[0];
    const float* u0   = (const float*)d_in[1];
    const float* p0   = (const float*)d_in[2];
    const float* tf   = (const float*)d_in[3];
    // d_in[4] = n_steps (fixed at 32)

    float* A    = (float*)d_out;
    float* B    = (float*)d_ws;                          // 3*NXC floats
    float* part = B + (size_t)3 * NXC;                   // 2*NBLK floats
    float* halo = part + 2 * NBLK;                       // 2*NBLK*6 floats
    unsigned* bar = (unsigned*)(halo + (size_t)2 * NBLK * 6);

    bar_zero<<<1, BLK, 0, stream>>>(bar);

    void* args[] = {(void*)&rho0, (void*)&u0, (void*)&p0, (void*)&tf,
                    (void*)&A, (void*)&B, (void*)&part, (void*)&halo,
                    (void*)&bar};
    hipLaunchCooperativeKernel((void*)euler_pers, dim3(NBLK), dim3(BLK),
                               args, 0, stream);
}

// Round 7
// 435.534 us; speedup vs baseline: 8.3135x; 1.2444x over previous
//
#include <hip/hip_runtime.h>

// 1D Euler, Roe flux + Harten entropy fix, 32 steps. Round 7:
// = round 4 (PASSING, 542 us, 52 VGPR, LDS-tiled persistent kernel with
// relaxed system-scope barrier) + register-light compute upgrades only.
//
// Rounds 5/6 (register-resident state) failed twice with d_out untouched:
// cooperative launch silently rejected -- true register allocation
// (arch VGPR + spill/AGPR on the unified file) breaks co-residency however
// generous the __launch_bounds__ margin. Round 4's shape is hardware-proven
// at exact capacity (1024 blocks, 37 KB LDS -> 4/CU). Minimal diff:
//  1. Fast transcendentals (v_rcp/v_rsq/v_sqrt builtins, ~1 ulp) replace
//     all IEEE div/sqrt expansions -- attacks the measured 64.6% VALUBusy.
//  2. dt via per-block atomicMax into 64 banked slots/step (33 monotone
//     rows, positive-float bits are uint-monotone); each wave loads 64
//     slots and shuffle-reduces. Replaces the 1024-element redundant scan.
//  3. p/(g-1) -> p*2.5f (exact constant).
// Everything else identical to round 4: LDS staging + per-cell precompute
// (s=sqrt(r), g=(E+p)/s), one flux per interface via LDS, halo cells and
// barrier words through relaxed SYSTEM-scope atomics (IC-coherent, no
// buffer_wbl2/inv), state ping-pong d_out/d_ws with own-tile-only cached
// access (persistent blocks never migrate).

#define NXC   1048576
#define BLK   256
#define TILE  1024
#define NBLK  (NXC / TILE)   // 1024 blocks = 4/CU (LDS ~37 KB), proven r4
#define GAM   1.4f
#define GM1   0.4f
#define IGM1  2.5f
#define CFLC  0.5f
#define DXC   1e-3f
#define EFIX  0.1f
#define NSTEPS 32
#define NSLOT  (NSTEPS + 1)
#define SLOTW  64

#define BAR1_N  64
#define BSTRIDE 32           // 128 B between barrier counters

__device__ __forceinline__ float frcp(float x){ return __builtin_amdgcn_rcpf(x); }
__device__ __forceinline__ float frsq(float x){ return __builtin_amdgcn_rsqf(x); }
__device__ __forceinline__ float fsqrt_(float x){ return __builtin_amdgcn_sqrtf(x); }

__device__ __forceinline__ float sysloadf(const float* p) {
    return __hip_atomic_load(p, __ATOMIC_RELAXED, __HIP_MEMORY_SCOPE_SYSTEM);
}
__device__ __forceinline__ void sysstoref(float* p, float v) {
    __hip_atomic_store(p, v, __ATOMIC_RELAXED, __HIP_MEMORY_SCOPE_SYSTEM);
}
__device__ __forceinline__ unsigned sysloadu(const unsigned* p) {
    return __hip_atomic_load(p, __ATOMIC_RELAXED, __HIP_MEMORY_SCOPE_SYSTEM);
}

__device__ __forceinline__ float wave_max(float v) {
    #pragma unroll
    for (int k = 32; k >= 1; k >>= 1)
        v = fmaxf(v, __shfl_xor(v, k));
    return v;
}

// Relaxed system-scope two-level barrier (round-4 verified). gen from 1.
__device__ __forceinline__ void gbar(unsigned* bar1, unsigned* bar2,
                                     unsigned* flag, int bid, unsigned gen) {
    __syncthreads();   // every wave drains vmcnt(0) before arriving
    if (threadIdx.x == 0) {
        unsigned o = __hip_atomic_fetch_add(
            &bar1[(bid & (BAR1_N - 1)) * BSTRIDE], 1u,
            __ATOMIC_RELAXED, __HIP_MEMORY_SCOPE_SYSTEM);
        if ((o & 15u) == 15u) {           // 1024/64 = 16 blocks per L1
            unsigned o2 = __hip_atomic_fetch_add(
                bar2, 1u, __ATOMIC_RELAXED, __HIP_MEMORY_SCOPE_SYSTEM);
            if ((o2 & 63u) == 63u)
                __hip_atomic_store(flag, gen, __ATOMIC_RELAXED,
                                   __HIP_MEMORY_SCOPE_SYSTEM);
        }
        while (__hip_atomic_load(flag, __ATOMIC_RELAXED,
                                 __HIP_MEMORY_SCOPE_SYSTEM) < gen)
            __builtin_amdgcn_s_sleep(2);
    }
    __syncthreads();
}

__global__ void ws_zero(unsigned* z) {
    const int n = (BAR1_N + 2) * BSTRIDE + NSLOT * SLOTW;
    for (int i = threadIdx.x; i < n; i += BLK) z[i] = 0u;
}

__global__ __launch_bounds__(BLK, 4) void euler_pers(
        const float* __restrict__ rho0, const float* __restrict__ u0,
        const float* __restrict__ p0, const float* __restrict__ tf,
        float* __restrict__ A,      // even states (= d_out)
        float* __restrict__ B,      // odd states (in d_ws)
        unsigned* __restrict__ slots,  // NSLOT x SLOTW banked amax slots
        float* __restrict__ halo,   // 2 * NBLK * 6 halo floats (IC)
        unsigned* __restrict__ bar) {
    __shared__ float sr[TILE + 2], su[TILE + 2], sp[TILE + 2];
    __shared__ float ss[TILE + 2], sg[TILE + 2], sfr[TILE + 2];
    __shared__ float fFr[TILE + 1], fFm[TILE + 1], fFe[TILE + 1];
    __shared__ float red[BLK / 64];
    unsigned* bar1 = bar;
    unsigned* bar2 = bar + BAR1_N * BSTRIDE;
    unsigned* flag = bar + (BAR1_N + 1) * BSTRIDE;

    const int tid  = threadIdx.x;
    const int bid  = blockIdx.x;
    const int base = bid * TILE;
    unsigned gen = 0;

    // ---- prepass: partial max of |u0|+c0 into slot row 0 ----
    float lm = 0.f;
    for (int j = tid; j < TILE; j += BLK) {
        int g = base + j;
        float ir = frcp(rho0[g]);
        lm = fmaxf(lm, fabsf(u0[g]) + fsqrt_(GAM * p0[g] * ir));
    }
    lm = wave_max(lm);
    if ((tid & 63) == 0) red[tid >> 6] = lm;
    __syncthreads();
    if (tid == 0)
        __hip_atomic_fetch_max(&slots[(size_t)(bid & (SLOTW - 1))],
            __float_as_uint(fmaxf(fmaxf(red[0], red[1]), fmaxf(red[2], red[3]))),
            __ATOMIC_RELAXED, __HIP_MEMORY_SCOPE_SYSTEM);
    float t = 0.f;
    const float tfin = *tf;
    gbar(bar1, bar2, flag, bid, ++gen);

    for (int k = 0; k < NSTEPS; ++k) {
        const int pk = k & 1;
        const float* src  = pk ? B : A;     // own tile only (k>=1)
        float*       dst  = pk ? A : B;     // own tile only
        const float* hin  = halo + (size_t)pk * (NBLK * 6);
        float*       hout = halo + (size_t)(1 - pk) * (NBLK * 6);

        // dt: one banked-slot load per lane; wave covers all 64 slots
        float av = __uint_as_float(
            sysloadu(&slots[(size_t)k * SLOTW + (tid & (SLOTW - 1))]));

        // stage tile + halo into LDS with per-cell precompute:
        //   ss = sqrt(rho), sg = (E+p)/sqrt(rho) = sqrt(rho)*H, sfr = rho*u
        for (int i = tid; i < TILE + 2; i += BLK) {
            float r_, u_, p_;
            if (k == 0) {                       // step 0: raw inputs
                int g = max(0, min(NXC - 1, base - 1 + i));
                r_ = rho0[g]; u_ = u0[g]; p_ = p0[g];
            } else if (i == 0) {                // left ghost
                if (bid == 0) {
                    r_ = src[base]; u_ = src[NXC + base]; p_ = src[2 * NXC + base];
                } else {
                    const float* h = hin + (size_t)(bid - 1) * 6 + 3;
                    r_ = sysloadf(h); u_ = sysloadf(h + 1); p_ = sysloadf(h + 2);
                }
            } else if (i == TILE + 1) {         // right ghost
                if (bid == NBLK - 1) {
                    int g = base + TILE - 1;
                    r_ = src[g]; u_ = src[NXC + g]; p_ = src[2 * NXC + g];
                } else {
                    const float* h = hin + (size_t)(bid + 1) * 6;
                    r_ = sysloadf(h); u_ = sysloadf(h + 1); p_ = sysloadf(h + 2);
                }
            } else {                            // own tile (local L2)
                int g = base + i - 1;
                r_ = src[g]; u_ = src[NXC + g]; p_ = src[2 * NXC + g];
            }
            float E  = p_ * IGM1 + 0.5f * r_ * u_ * u_;
            float rs = frsq(r_);
            sr[i] = r_; su[i] = u_; sp[i] = p_;
            ss[i] = r_ * rs; sg[i] = (E + p_) * rs; sfr[i] = r_ * u_;
        }
        __syncthreads();    // LDS staging complete

        float amax = wave_max(av);
        float dt = fminf(CFLC * DXC / amax, fmaxf(tfin - t, 0.f));
        t += dt;
        float dtdx = dt / DXC;

        // one Roe flux per interface
        for (int i = tid; i < TILE + 1; i += BLK) {
            float sL = ss[i], sR = ss[i + 1];
            float uL = su[i], uR = su[i + 1];
            float invden = frcp(sL + sR);
            float ur = (sL * uL + sR * uR) * invden;
            float Hr = (sg[i] + sg[i + 1]) * invden;
            float c  = fsqrt_(fmaxf(GM1 * (Hr - 0.5f * ur * ur), 1e-10f));
            float eps = EFIX * c;
            float l1 = ur - c, l3 = ur + c;
            float a1 = fsqrt_(l1 * l1 + eps * eps);
            float a2 = fsqrt_(ur * ur + eps * eps);
            float a3 = fsqrt_(l3 * l3 + eps * eps);
            float drho = sr[i + 1] - sr[i];
            float du   = uR - uL;
            float dp   = sp[i + 1] - sp[i];
            float c2 = c * c;
            float inv2c2 = frcp(c2 + c2);
            float al2 = drho - (dp + dp) * inv2c2;
            float tcd = c * sr[i + 1] * du;
            float al1 = (dp - tcd) * inv2c2;
            float al3 = (dp + tcd) * inv2c2;
            float FrL = sfr[i], FrR = sfr[i + 1];
            float FmL = FrL * uL + sp[i], FmR = FrR * uR + sp[i + 1];
            float FeL = uL * (sg[i] * sL), FeR = uR * (sg[i + 1] * sR);
            float w1 = a1 * al1, w2 = a2 * al2, w3 = a3 * al3;
            float dr = w1 + w2 + w3;
            float dm = w1 * l1 + w2 * ur + w3 * l3;
            float de = w1 * (Hr - ur * c) + w2 * (0.5f * ur * ur)
                     + w3 * (Hr + ur * c);
            fFr[i] = 0.5f * (FrL + FrR - dr);
            fFm[i] = 0.5f * (FmL + FmR - dm);
            fFe[i] = 0.5f * (FeL + FeR - de);
        }
        __syncthreads();

        // conservative update -> primitives (own tile, cached stores);
        // edge cells also go to the system-scope halo slots.
        float nm = 0.f;
        for (int j = tid; j < TILE; j += BLK) {
            float rho = sr[j + 1], u = su[j + 1], p = sp[j + 1];
            float E = sg[j + 1] * ss[j + 1] - p;          // (E+p) - p
            float rho2  = rho        - dtdx * (fFr[j + 1] - fFr[j]);
            float rhou2 = sfr[j + 1] - dtdx * (fFm[j + 1] - fFm[j]);
            float E2    = E          - dtdx * (fFe[j + 1] - fFe[j]);
            float rs2 = frsq(rho2);
            float ir  = rs2 * rs2;
            float u2 = rhou2 * ir;
            float p2 = GM1 * (E2 - 0.5f * rho2 * u2 * u2);
            int g = base + j;
            dst[g] = rho2;
            dst[NXC + g] = u2;
            dst[2 * NXC + g] = p2;
            if (j == 0) {
                float* h = hout + (size_t)bid * 6;
                sysstoref(h, rho2); sysstoref(h + 1, u2); sysstoref(h + 2, p2);
            }
            if (j == TILE - 1) {
                float* h = hout + (size_t)bid * 6 + 3;
                sysstoref(h, rho2); sysstoref(h + 1, u2); sysstoref(h + 2, p2);
            }
            nm = fmaxf(nm, fabsf(u2) + fsqrt_(GAM * p2 * ir));
        }
        nm = wave_max(nm);
        if ((tid & 63) == 0) red[tid >> 6] = nm;
        __syncthreads();
        if (tid == 0)
            __hip_atomic_fetch_max(
                &slots[(size_t)(k + 1) * SLOTW + (bid & (SLOTW - 1))],
                __float_as_uint(fmaxf(fmaxf(red[0], red[1]),
                                      fmaxf(red[2], red[3]))),
                __ATOMIC_RELAXED, __HIP_MEMORY_SCOPE_SYSTEM);

        if (k < NSTEPS - 1) gbar(bar1, bar2, flag, bid, ++gen);
    }
    // k=31 wrote dst=A=d_out; end-of-kernel flush makes it host-visible.
}

extern "C" void kernel_launch(void* const* d_in, const int* in_sizes, int n_in,
                              void* d_out, int out_size, void* d_ws, size_t ws_size,
                              hipStream_t stream) {
    const float* rho0 = (const float*)d_in[0];
    const float* u0   = (const float*)d_in[1];
    const float* p0   = (const float*)d_in[2];
    const float* tf   = (const float*)d_in[3];
    // d_in[4] = n_steps (fixed at 32)

    float* A      = (float*)d_out;
    float* B      = (float*)d_ws;                        // 3*NXC floats
    unsigned* bar = (unsigned*)(B + (size_t)3 * NXC);    // (64+2)*32 uints
    unsigned* slots = bar + (BAR1_N + 2) * BSTRIDE;      // 33*64 uints
    float* halo   = (float*)(slots + NSLOT * SLOTW);     // 2*NBLK*6 floats

    ws_zero<<<1, BLK, 0, stream>>>(bar);

    void* args[] = {(void*)&rho0, (void*)&u0, (void*)&p0, (void*)&tf,
                    (void*)&A, (void*)&B, (void*)&slots, (void*)&halo,
                    (void*)&bar};
    hipLaunchCooperativeKernel((void*)euler_pers, dim3(NBLK), dim3(BLK),
                               args, 0, stream);
}

// Round 8
// 399.077 us; speedup vs baseline: 9.0730x; 1.0914x over previous
//
#include <hip/hip_runtime.h>

// 1D Euler, Roe flux + Harten entropy fix, 32 steps. Round 8:
// NO-LDS step body + launch-safety net.
//
// Round 7 (354 us, PASSING): VALUBusy 44%, HBM ~1% -> residual time is LDS
// round-trips (~108 LDS ops/thread/step) + 3 syncthreads/step. This round:
//  - Thread t loads its 6-cell window (cells 4t-1..4t+4) straight from
//    global (own tile = own-XCD L2; 3 aligned float4 + 2 scalars), computes
//    5 Roe fluxes in registers (shared interfaces recomputed from
//    bit-identical inputs -> bit-identical values; no exchange), updates
//    its 4 cells, stores 3 float4. LDS body = 4-float reduction scratch;
//    1 syncthreads/step. Registers are short-lived (state does NOT persist
//    across the barrier, unlike failed rounds 5/6).
//  - Cross-block cells still via relaxed SYSTEM-scope halo slots (IC-
//    coherent, no wbl2/inv); dt via banked atomicMax slot rows (round 7).
//  - SAFETY NET for the silent cooperative-launch rejection that killed
//    rounds 5/6: host queries hipOccupancyMaxActiveBlocksPerMultiprocessor
//    (deterministic, capture-safe). If 1024 blocks don't fit, fall back to
//    33 plain per-step dispatches of the SAME step_core (kernel boundaries
//    provide coherence; t handed off via tbuf, amax via slot rows).

#define NXC   1048576
#define BLK   256
#define CPT   4
#define TILE  (BLK*CPT)      // 1024
#define NBLK  (NXC/TILE)     // 1024 blocks; coop path needs 4/CU
#define GAM   1.4f
#define GM1   0.4f
#define IGM1  2.5f
#define CFLC  0.5f
#define DXC   1e-3f
#define EFIX  0.1f
#define NSTEPS 32
#define NSLOT  (NSTEPS + 1)
#define SLOTW  64

#define BAR1_N  64
#define BSTRIDE 32           // 128 B between barrier counters

__device__ __forceinline__ float frcp(float x){ return __builtin_amdgcn_rcpf(x); }
__device__ __forceinline__ float frsq(float x){ return __builtin_amdgcn_rsqf(x); }
__device__ __forceinline__ float fsqrt_(float x){ return __builtin_amdgcn_sqrtf(x); }

__device__ __forceinline__ float sysloadf(const float* p) {
    return __hip_atomic_load(p, __ATOMIC_RELAXED, __HIP_MEMORY_SCOPE_SYSTEM);
}
__device__ __forceinline__ void sysstoref(float* p, float v) {
    __hip_atomic_store(p, v, __ATOMIC_RELAXED, __HIP_MEMORY_SCOPE_SYSTEM);
}
__device__ __forceinline__ unsigned sysloadu(const unsigned* p) {
    return __hip_atomic_load(p, __ATOMIC_RELAXED, __HIP_MEMORY_SCOPE_SYSTEM);
}

__device__ __forceinline__ float wave_max(float v) {
    #pragma unroll
    for (int k = 32; k >= 1; k >>= 1)
        v = fmaxf(v, __shfl_xor(v, k));
    return v;
}

// Relaxed system-scope two-level barrier (proven rounds 4/7). gen from 1.
__device__ __forceinline__ void gbar(unsigned* bar1, unsigned* bar2,
                                     unsigned* flag, int bid, unsigned gen) {
    __syncthreads();   // every wave drains vmcnt(0) before arriving
    if (threadIdx.x == 0) {
        unsigned o = __hip_atomic_fetch_add(
            &bar1[(bid & (BAR1_N - 1)) * BSTRIDE], 1u,
            __ATOMIC_RELAXED, __HIP_MEMORY_SCOPE_SYSTEM);
        if ((o & 15u) == 15u) {           // 1024/64 = 16 blocks per L1
            unsigned o2 = __hip_atomic_fetch_add(
                bar2, 1u, __ATOMIC_RELAXED, __HIP_MEMORY_SCOPE_SYSTEM);
            if ((o2 & 63u) == 63u)
                __hip_atomic_store(flag, gen, __ATOMIC_RELAXED,
                                   __HIP_MEMORY_SCOPE_SYSTEM);
        }
        while (__hip_atomic_load(flag, __ATOMIC_RELAXED,
                                 __HIP_MEMORY_SCOPE_SYSTEM) < gen)
            __builtin_amdgcn_s_sleep(2);
    }
    __syncthreads();
}

__global__ void ws_zero(unsigned* z) {
    const int n = (BAR1_N + 2) * BSTRIDE + NSLOT * SLOTW + NSLOT;
    for (int i = threadIdx.x; i < n; i += BLK) z[i] = 0u;
}

// ---- prepass: amax of |u0|+c0 into slot row 0 (4 cells/thread) ----
__device__ __forceinline__ void prepass_core(
        const float* __restrict__ rho0, const float* __restrict__ u0,
        const float* __restrict__ p0, unsigned* __restrict__ slots,
        float* __restrict__ red) {
    const int tid = threadIdx.x, bid = blockIdx.x;
    const int c0 = bid * TILE + CPT * tid;
    float4 r4 = *(const float4*)(rho0 + c0);
    float4 u4 = *(const float4*)(u0 + c0);
    float4 p4 = *(const float4*)(p0 + c0);
    const float ra[4] = {r4.x, r4.y, r4.z, r4.w};
    const float ua[4] = {u4.x, u4.y, u4.z, u4.w};
    const float pa[4] = {p4.x, p4.y, p4.z, p4.w};
    float nm = 0.f;
    #pragma unroll
    for (int c = 0; c < CPT; ++c)
        nm = fmaxf(nm, fabsf(ua[c]) + fsqrt_(GAM * pa[c] * frcp(ra[c])));
    nm = wave_max(nm);
    if ((tid & 63) == 0) red[tid >> 6] = nm;
    __syncthreads();
    if (tid == 0)
        __hip_atomic_fetch_max(&slots[(size_t)(bid & (SLOTW - 1))],
            __float_as_uint(fmaxf(fmaxf(red[0], red[1]), fmaxf(red[2], red[3]))),
            __ATOMIC_RELAXED, __HIP_MEMORY_SCOPE_SYSTEM);
}

// ---- one full step for this thread's 4 cells; returns dt (all threads) --
__device__ __forceinline__ float step_core(
        int k, int bid, int tid,
        const float* __restrict__ rs, const float* __restrict__ us,
        const float* __restrict__ ps, float* __restrict__ dst,
        const float* __restrict__ hin, float* __restrict__ hout,
        unsigned* __restrict__ slots, float t, float tfin,
        float* __restrict__ red) {
    const int base = bid * TILE;
    const int c0 = base + CPT * tid;

    // dt slot load first (hide IC latency under the state loads)
    float av = __uint_as_float(
        sysloadu(&slots[(size_t)k * SLOTW + (tid & (SLOTW - 1))]));

    // 6-cell window: idx 0..5 = cells c0-1 .. c0+4
    float rr[6], uu[6], pp[6];
    {
        float4 r4 = *(const float4*)(rs + c0);
        float4 u4 = *(const float4*)(us + c0);
        float4 p4 = *(const float4*)(ps + c0);
        rr[1] = r4.x; rr[2] = r4.y; rr[3] = r4.z; rr[4] = r4.w;
        uu[1] = u4.x; uu[2] = u4.y; uu[3] = u4.z; uu[4] = u4.w;
        pp[1] = p4.x; pp[2] = p4.y; pp[3] = p4.z; pp[4] = p4.w;
    }
    if (k > 0 && tid == 0 && bid > 0) {          // cross-block left: halo
        const float* h = hin + (size_t)(bid - 1) * 6 + 3;
        rr[0] = sysloadf(h); uu[0] = sysloadf(h + 1); pp[0] = sysloadf(h + 2);
    } else {                                     // in-tile / input / clamp
        int g = max(c0 - 1, 0);
        rr[0] = rs[g]; uu[0] = us[g]; pp[0] = ps[g];
    }
    if (k > 0 && tid == BLK - 1 && bid < NBLK - 1) {  // cross-block right
        const float* h = hin + (size_t)(bid + 1) * 6;
        rr[5] = sysloadf(h); uu[5] = sysloadf(h + 1); pp[5] = sysloadf(h + 2);
    } else {
        int g = min(c0 + CPT, NXC - 1);
        rr[5] = rs[g]; uu[5] = us[g]; pp[5] = ps[g];
    }

    // per-cell precompute: s = sqrt(r), g = (E+p)/sqrt(r) = sqrt(r)*H
    float ss[6], gg[6];
    #pragma unroll
    for (int i = 0; i < 6; ++i) {
        float E = pp[i] * IGM1 + 0.5f * rr[i] * uu[i] * uu[i];
        float q = frsq(rr[i]);
        ss[i] = rr[i] * q;
        gg[i] = (E + pp[i]) * q;
    }

    // 5 Roe fluxes (interfaces left of cells 1..4, plus right of cell 4)
    float Fr[5], Fm[5], Fe[5];
    #pragma unroll
    for (int j = 0; j < 5; ++j) {
        float sL = ss[j], sR = ss[j + 1];
        float uL = uu[j], uR = uu[j + 1];
        float invden = frcp(sL + sR);
        float ur = (sL * uL + sR * uR) * invden;
        float Hr = (gg[j] + gg[j + 1]) * invden;
        float c  = fsqrt_(fmaxf(GM1 * (Hr - 0.5f * ur * ur), 1e-10f));
        float eps = EFIX * c;
        float l1 = ur - c, l3 = ur + c;
        float a1 = fsqrt_(l1 * l1 + eps * eps);
        float a2 = fsqrt_(ur * ur + eps * eps);
        float a3 = fsqrt_(l3 * l3 + eps * eps);
        float drho = rr[j + 1] - rr[j];
        float du   = uR - uL;
        float dp   = pp[j + 1] - pp[j];
        float c2 = c * c;
        float inv2c2 = frcp(c2 + c2);
        float al2 = drho - (dp + dp) * inv2c2;
        float tcd = c * rr[j + 1] * du;
        float al1 = (dp - tcd) * inv2c2;
        float al3 = (dp + tcd) * inv2c2;
        float FrL = rr[j] * uL, FrR = rr[j + 1] * uR;
        float FmL = FrL * uL + pp[j], FmR = FrR * uR + pp[j + 1];
        float FeL = uL * (gg[j] * sL), FeR = uR * (gg[j + 1] * sR);
        float w1 = a1 * al1, w2 = a2 * al2, w3 = a3 * al3;
        Fr[j] = 0.5f * (FrL + FrR - (w1 + w2 + w3));
        Fm[j] = 0.5f * (FmL + FmR - (w1 * l1 + w2 * ur + w3 * l3));
        Fe[j] = 0.5f * (FeL + FeR - (w1 * (Hr - ur * c) + w2 * (0.5f * ur * ur)
                                     + w3 * (Hr + ur * c)));
    }

    // dt from the 64 banked slots (each lane holds one slot)
    float amax = wave_max(av);
    float dt = fminf(CFLC * DXC / amax, fmaxf(tfin - t, 0.f));
    float dtdx = dt / DXC;

    // conservative update -> primitives; stores
    float o_r[4], o_u[4], o_p[4];
    float nm = 0.f;
    #pragma unroll
    for (int i = 1; i <= 4; ++i) {
        float E  = gg[i] * ss[i] - pp[i];            // (E+p) - p
        float r2 = rr[i]         - dtdx * (Fr[i] - Fr[i - 1]);
        float m2 = rr[i] * uu[i] - dtdx * (Fm[i] - Fm[i - 1]);
        float E2 = E             - dtdx * (Fe[i] - Fe[i - 1]);
        float q2 = frsq(r2);
        float ir = q2 * q2;
        float u2 = m2 * ir;
        float p2 = GM1 * (E2 - 0.5f * r2 * u2 * u2);
        o_r[i - 1] = r2; o_u[i - 1] = u2; o_p[i - 1] = p2;
        nm = fmaxf(nm, fabsf(u2) + fsqrt_(GAM * p2 * ir));
    }
    *(float4*)(dst + c0)           = make_float4(o_r[0], o_r[1], o_r[2], o_r[3]);
    *(float4*)(dst + NXC + c0)     = make_float4(o_u[0], o_u[1], o_u[2], o_u[3]);
    *(float4*)(dst + 2 * NXC + c0) = make_float4(o_p[0], o_p[1], o_p[2], o_p[3]);
    if (tid == 0) {
        float* h = hout + (size_t)bid * 6;
        sysstoref(h, o_r[0]); sysstoref(h + 1, o_u[0]); sysstoref(h + 2, o_p[0]);
    }
    if (tid == BLK - 1) {
        float* h = hout + (size_t)bid * 6 + 3;
        sysstoref(h, o_r[3]); sysstoref(h + 1, o_u[3]); sysstoref(h + 2, o_p[3]);
    }
    nm = wave_max(nm);
    if ((tid & 63) == 0) red[tid >> 6] = nm;
    __syncthreads();
    if (tid == 0)
        __hip_atomic_fetch_max(
            &slots[(size_t)(k + 1) * SLOTW + (bid & (SLOTW - 1))],
            __float_as_uint(fmaxf(fmaxf(red[0], red[1]), fmaxf(red[2], red[3]))),
            __ATOMIC_RELAXED, __HIP_MEMORY_SCOPE_SYSTEM);
    return dt;
}

// ---------------- persistent cooperative kernel ----------------
__global__ __launch_bounds__(BLK, 4) void euler_pers(
        const float* __restrict__ rho0, const float* __restrict__ u0,
        const float* __restrict__ p0, const float* __restrict__ tf,
        float* __restrict__ A, float* __restrict__ B,
        unsigned* __restrict__ slots, float* __restrict__ halo,
        unsigned* __restrict__ bar) {
    __shared__ float red[4];
    unsigned* bar1 = bar;
    unsigned* bar2 = bar + BAR1_N * BSTRIDE;
    unsigned* flag = bar + (BAR1_N + 1) * BSTRIDE;
    const int tid = threadIdx.x, bid = blockIdx.x;
    unsigned gen = 0;

    prepass_core(rho0, u0, p0, slots, red);
    float t = 0.f;
    const float tfin = *tf;
    gbar(bar1, bar2, flag, bid, ++gen);

    for (int k = 0; k < NSTEPS; ++k) {
        const int pk = k & 1;
        const float *rs, *us, *ps;
        if (k == 0) { rs = rho0; us = u0; ps = p0; }
        else { const float* s = pk ? B : A; rs = s; us = s + NXC; ps = s + 2 * NXC; }
        float* dst = pk ? A : B;                       // k=31 -> A = d_out
        const float* hin = halo + (size_t)pk * (NBLK * 6);
        float* hout = halo + (size_t)(1 - pk) * (NBLK * 6);
        float dt = step_core(k, bid, tid, rs, us, ps, dst, hin, hout,
                             slots, t, tfin, red);
        t += dt;
        if (k < NSTEPS - 1) gbar(bar1, bar2, flag, bid, ++gen);
    }
}

// ---------------- fallback: plain per-step dispatches ----------------
__global__ __launch_bounds__(BLK) void prepass_k(
        const float* __restrict__ rho0, const float* __restrict__ u0,
        const float* __restrict__ p0, unsigned* __restrict__ slots) {
    __shared__ float red[4];
    prepass_core(rho0, u0, p0, slots, red);
}

__global__ __launch_bounds__(BLK) void step_k(
        int k, const float* __restrict__ rs, const float* __restrict__ us,
        const float* __restrict__ ps, float* __restrict__ dst,
        const float* __restrict__ hin, float* __restrict__ hout,
        unsigned* __restrict__ slots, const float* __restrict__ tf,
        float* __restrict__ tbuf) {
    __shared__ float red[4];
    float t = tbuf[k];
    float tfin = *tf;
    float dt = step_core(k, blockIdx.x, threadIdx.x, rs, us, ps, dst,
                         hin, hout, slots, t, tfin, red);
    if (blockIdx.x == 0 && threadIdx.x == 0) tbuf[k + 1] = t + dt;
}

extern "C" void kernel_launch(void* const* d_in, const int* in_sizes, int n_in,
                              void* d_out, int out_size, void* d_ws, size_t ws_size,
                              hipStream_t stream) {
    const float* rho0 = (const float*)d_in[0];
    const float* u0   = (const float*)d_in[1];
    const float* p0   = (const float*)d_in[2];
    const float* tf   = (const float*)d_in[3];
    // d_in[4] = n_steps (fixed at 32)

    float* A        = (float*)d_out;
    float* B        = (float*)d_ws;                          // 3*NXC floats
    unsigned* bar   = (unsigned*)(B + (size_t)3 * NXC);      // (64+2)*32
    unsigned* slots = bar + (BAR1_N + 2) * BSTRIDE;          // 33*64
    float* tbuf     = (float*)(slots + NSLOT * SLOTW);       // 33
    float* halo     = tbuf + NSLOT;                          // 2*NBLK*6

    ws_zero<<<1, BLK, 0, stream>>>(bar);

    // Deterministic, capture-safe co-residency check (rounds 5/6 failed on
    // a silently rejected cooperative launch).
    int dev = 0; (void)hipGetDevice(&dev);
    int cus = 0;
    (void)hipDeviceGetAttribute(&cus, hipDeviceAttributeMultiprocessorCount, dev);
    int occ = 0;
    (void)hipOccupancyMaxActiveBlocksPerMultiprocessor(&occ, euler_pers, BLK, 0);

    bool done = false;
    if (occ > 0 && cus > 0 && (long)occ * cus >= NBLK) {
        void* args[] = {(void*)&rho0, (void*)&u0, (void*)&p0, (void*)&tf,
                        (void*)&A, (void*)&B, (void*)&slots, (void*)&halo,
                        (void*)&bar};
        done = hipLaunchCooperativeKernel((void*)euler_pers, dim3(NBLK),
                                          dim3(BLK), args, 0, stream)
               == hipSuccess;
    }
    if (!done) {
        prepass_k<<<NBLK, BLK, 0, stream>>>(rho0, u0, p0, slots);
        for (int k = 0; k < NSTEPS; ++k) {
            const int pk = k & 1;
            const float *rs, *us, *ps;
            if (k == 0) { rs = rho0; us = u0; ps = p0; }
            else { const float* s = pk ? B : A; rs = s; us = s + NXC; ps = s + 2 * NXC; }
            float* dst = pk ? A : B;
            const float* hin = halo + (size_t)pk * (NBLK * 6);
            float* hout = halo + (size_t)(1 - pk) * (NBLK * 6);
            step_k<<<NBLK, BLK, 0, stream>>>(k, rs, us, ps, dst, hin, hout,
                                             slots, tf, tbuf);
        }
    }
}